// Round 7
// baseline (966.514 us; speedup 1.0000x reference)
//
#include <hip/hip_runtime.h>

#define TPB 512

// ---- workspace layout (float/uint indices), total 133224 < proven 145152 ----
#define OFF_CV      0        // fp32 [2][40][32] card_emb @ v^T (h2t, t2h)
#define OFF_POSB    2560     // u32  [40][32] packed bf16 pairs: b_hproj[d]+pos[i][d]
#define OFF_G       3840     // u32  [2][4][40][20] packed bf16 bilinear table (pre-scaled)
#define OFF_U       10240    // fp32 [2][4][40]
#define OFF_V       10560    // fp32 [2][4][40]
#define OFF_CTB     10880    // fp32 [2][4]
#define OFF_FRHP    10888    // u32 hproj frags [2pl][2kt][4nt][64][4] = 4096
#define OFF_FRAG    14984    // u32 MFMA B-fragments
#define FR_QKV      0        //   [p2][kt2][nt12][64][4]  enc_win rows 0..191
#define FR_OUT      12288    //   [p2][kt2][nt4][64][4]   enc_wout
#define FR_FF1      16384    //   [p2][kt2][nt8][64][4]   w_ff1
#define FR_FF2      24576    //   [p2][kt4][nt4][64][4]   w_ff2
#define OFF_ONES    47752    // u32 [2kt][64][4] ones-frag (k<40 -> 1.0bf16, else 0)
#define OFF_MERGE   48264    // fp32 [224][64]
#define OFF_STATS   62600    // u32 [383][32] packed bf16 pairs of w_stats^T
#define OFF_COMB    74856    // fp32 [56][256][4]: [jq][n][c] = w_comb[n][jq*4+c]
#define OFF_WO2     132200   // u32 [2][32][16] packed bf16: wout_t[e][2u],[2u+1]
#define WS_TOTAL    133224

// ---- LDS overlay (bytes), total 40860 -> 4 blocks/CU (was 52520 -> 3) ----
// All region trims rely on: garbage A-rows (m>=40) are M-confined in MFMA
// (pollute only discarded D rows, NaN-safe); K-dim garbage is excluded by
// guarded loads (PV a1, R4.5 B) and explicit zeros (Vfrag k>=40).
// sA bf16us [40][64] @0: hseq (S1-R6) -> x post-LN1 (R7-R9) -> x2 (R10+).
// Transformer intermediates in bf16: output-attenuated ~30x via 0.02 w_comb.
#define SA_OFF    0        // 5120
// X 5120..16384: histH/L (S1-R3) -> QPL+KF (R4-R4.5) -> OH (R5-R6) -> FF1P
#define HISTH_OFF 5120     // [40] stride 136 = 5440
#define HISTL_OFF 10560    // 5440 (ends 16000; row-spill reads M-confined)
#define QPL_OFF   5120     // [4][40][16]us = 5120 (Q hi, per-head rows)
#define KF_OFF    10240    // [4][3][32][8]us = 6144 (K B-frag, lanes 0..31)
#define OH_OFF    5120     // [40] stride 144 = 5760 (attn O, hi only)
#define FF1P_OFF  5120     // [40] stride 272 = 10880 (i<40 write guard!)
// Y 16384..29184: DH/DL planes (R3-R4) -> P bf16 (R4.5-R5) -> DH/DL (R7-R8)
#define DH_OFF    16384    // [40] stride 144 = 5760
#define DL_OFF    22144    // 5760 (ends 27904)
#define P_OFF     16384    // [4][40][40]us stride 80 = 12800 (ends 29184)
// Z 29184..37376: Vfrag bf16 [4][2][64][8]us (R4-R5) -> preLN1 bf16us
//                 [40][64] (R6-R7) -> preLN2 (R9-R10)
#define Z_OFF     29184
#define VF_OFF    29184
// tail
#define BNK_OFF   37376    // [128] f32: stats bank2 [0..64), merge bank2 [64..128)
#define SHT_OFF   37888    // s_ht [165]
#define SOM_OFF   38548    // s_om [128] (even/odd-i banks)
#define SSM_OFF   39060    // s_sm [224]
#define SCB_OFF   39956    // s_cb [224]
#define SCNT_OFF  40852    // s_cnt [2]
#define R12_OFF   37888    // R12 partials [2][256] overlay s_ht..s_sm (dead by R12)
#define SMEM_BYTES 40860

typedef __attribute__((ext_vector_type(8))) short bf16x8;
typedef __attribute__((ext_vector_type(4))) float f32x4;

struct P {
  const float *obs, *seat, *ce, *wch, *bch, *wcc, *bcc,
    *h2t_win, *h2t_bin, *h2t_wout, *h2t_bout,
    *t2h_win, *t2h_bin, *t2h_wout, *t2h_bout,
    *w_merge, *b_merge, *w_hproj, *b_hproj, *pos,
    *enc_win, *enc_bin, *enc_wout, *enc_bout,
    *ln1_g, *ln1_b, *w_ff1, *b_ff1, *w_ff2, *b_ff2, *ln2_g, *ln2_b,
    *w_stats, *b_stats, *w_seat, *b_seat, *w_comb, *b_comb;
  const float* ws;
  float* out;
};

__device__ __host__ inline unsigned bfpack(float a, float b, int plane) {
  unsigned ua = __float_as_uint(a) & 0xFFFF0000u;
  unsigned ub = __float_as_uint(b) & 0xFFFF0000u;
  if (plane == 0) return (ua >> 16) | ub;
  float ra = a - __uint_as_float(ua), rb = b - __uint_as_float(ub);
  return (__float_as_uint(ra) >> 16) | (__float_as_uint(rb) & 0xFFFF0000u);
}

__device__ __host__ inline unsigned short bf16rne(float x) {
  unsigned u = __float_as_uint(x);
  return (unsigned short)((u + 0x7FFFu + ((u >> 16) & 1u)) >> 16);
}

__device__ __host__ inline unsigned packrne(float a, float b) {
  return (unsigned)bf16rne(a) | ((unsigned)bf16rne(b) << 16);
}

__device__ inline float bf_lo(unsigned u) { return __uint_as_float(u << 16); }
__device__ inline float bf_hi(unsigned u) { return __uint_as_float(u & 0xFFFF0000u); }
__device__ inline float bfus(unsigned short u) {
  return __uint_as_float(((unsigned)u) << 16);
}

__device__ inline bf16x8 ld_b64x2(const char* pp) {  // 8B-aligned 16B LDS load
  bf16x8 v;
  *((uint2*)&v) = *(const uint2*)(pp);
  *(((uint2*)&v) + 1) = *(const uint2*)(pp + 8);
  return v;
}

#define CSCALE 0.35355339059327373f  /* 1/sqrt(8) */

// One-off prep (batch-independent).
__global__ void prep_kernel(P p, float* ws) {
  int t = blockIdx.x * blockDim.x + threadIdx.x;
  if (t >= WS_TOTAL) return;
  unsigned* wsu = (unsigned*)ws;
  if (t < OFF_POSB) {                       // cv: [a][i][d] = ce[i] . wv_row(d)
    int a = t / 1280, rem = t - a * 1280;
    int i = rem >> 5, d = rem & 31;
    const float* win = a ? p.t2h_win : p.h2t_win;
    const float* wr = win + (64 + d) * 32;
    const float* cr = p.ce + i * 32;
    float acc = 0.f;
    #pragma unroll
    for (int j = 0; j < 32; ++j) acc += cr[j] * wr[j];
    ws[t] = acc;
  } else if (t < OFF_G) {                   // posb packed bf16 pairs
    int r = t - OFF_POSB; int i = r >> 5, u = r & 31;
    float a = p.b_hproj[2 * u] + p.pos[i * 64 + 2 * u];
    float b = p.b_hproj[2 * u + 1] + p.pos[i * 64 + 2 * u + 1];
    wsu[t] = packrne(a, b);
  } else if (t < OFF_U) {                   // G packed (pre-scaled)
    int r = t - OFF_G;
    int u = r % 20; int i = (r / 20) % 40; int h = (r / 800) & 3; int a = r / 3200;
    const float* win = a ? p.t2h_win : p.h2t_win;
    const float* cri = p.ce + i * 32;
    float g2[2];
    #pragma unroll
    for (int half = 0; half < 2; ++half) {
      int j = 2 * u + half;
      const float* crj = p.ce + j * 32;
      float g = 0.f;
      for (int e = 0; e < 8; ++e) {
        const float* wq = win + (h * 8 + e) * 32;
        const float* wk = win + (32 + h * 8 + e) * 32;
        float pq = 0.f, pk = 0.f;
        for (int m = 0; m < 32; ++m) { pq += cri[m] * wq[m]; pk += crj[m] * wk[m]; }
        g += pq * pk;
      }
      g2[half] = g * CSCALE;
    }
    wsu[t] = packrne(g2[0], g2[1]);
  } else if (t < OFF_V) {                   // u[a][h][i]
    int r = t - OFF_U; int i = r % 40; int h = (r / 40) & 3; int a = r / 160;
    const float* win = a ? p.t2h_win : p.h2t_win;
    const float* bin = a ? p.t2h_bin : p.h2t_bin;
    const float* cri = p.ce + i * 32;
    float u = 0.f;
    for (int e = 0; e < 8; ++e) {
      const float* wq = win + (h * 8 + e) * 32;
      float pq = 0.f;
      for (int m = 0; m < 32; ++m) pq += cri[m] * wq[m];
      u += pq * bin[32 + h * 8 + e];
    }
    ws[t] = u * CSCALE;
  } else if (t < OFF_CTB) {                 // v[a][h][j]
    int r = t - OFF_V; int j = r % 40; int h = (r / 40) & 3; int a = r / 160;
    const float* win = a ? p.t2h_win : p.h2t_win;
    const float* bin = a ? p.t2h_bin : p.h2t_bin;
    const float* crj = p.ce + j * 32;
    float v = 0.f;
    for (int e = 0; e < 8; ++e) {
      const float* wk = win + (32 + h * 8 + e) * 32;
      float pk = 0.f;
      for (int m = 0; m < 32; ++m) pk += crj[m] * wk[m];
      v += pk * bin[h * 8 + e];
    }
    ws[t] = v * CSCALE;
  } else if (t < OFF_FRHP) {                // c[a][h]
    int r = t - OFF_CTB; int h = r & 3; int a = r >> 2;
    const float* bin = a ? p.t2h_bin : p.h2t_bin;
    float c = 0.f;
    for (int e = 0; e < 8; ++e) c += bin[h * 8 + e] * bin[32 + h * 8 + e];
    ws[t] = c * CSCALE;
  } else if (t < OFF_FRAG) {                // hproj B-frags (k 61..63 zero)
    int r = t - OFF_FRHP;
    int plane = r >> 11; r &= 2047; int kt = r >> 10; r &= 1023;
    int nt = r >> 8; r &= 255; int lane = r >> 2; int u = r & 3;
    int k = kt * 32 + (lane >> 4) * 8 + u * 2;
    int n = nt * 16 + (lane & 15);
    float a = (k < 61) ? p.w_hproj[n * 61 + k] : 0.f;
    float b = (k + 1 < 61) ? p.w_hproj[n * 61 + k + 1] : 0.f;
    wsu[t] = bfpack(a, b, plane);
  } else if (t < OFF_ONES) {                // main B-frags
    int r = t - OFF_FRAG;
    int plane, kt, nt, lane, u;
    const float* src; int ldk;
    if (r < FR_OUT) {
      plane = r / 6144; r %= 6144; kt = r / 3072; r %= 3072;
      nt = r >> 8; r &= 255; lane = r >> 2; u = r & 3;
      src = p.enc_win; ldk = 64;
    } else if (r < FR_FF1) {
      r -= FR_OUT; plane = r >> 11; r &= 2047; kt = r >> 10; r &= 1023;
      nt = r >> 8; r &= 255; lane = r >> 2; u = r & 3;
      src = p.enc_wout; ldk = 64;
    } else if (r < FR_FF2) {
      r -= FR_FF1; plane = r >> 12; r &= 4095; kt = r >> 11; r &= 2047;
      nt = r >> 8; r &= 255; lane = r >> 2; u = r & 3;
      src = p.w_ff1; ldk = 64;
    } else {
      r -= FR_FF2; plane = r >> 12; r &= 4095; kt = r >> 10; r &= 1023;
      nt = r >> 8; r &= 255; lane = r >> 2; u = r & 3;
      src = p.w_ff2; ldk = 128;
    }
    int k = kt * 32 + (lane >> 4) * 8 + u * 2;
    int n = nt * 16 + (lane & 15);
    float a = src[n * ldk + k], b = src[n * ldk + k + 1];
    wsu[t] = bfpack(a, b, plane);
  } else if (t < OFF_MERGE) {               // ones-frag for PV den
    int r = t - OFF_ONES;
    int kt = r >> 8, rr = r & 255;
    int lane = rr >> 2, u = rr & 3;
    int k = kt * 32 + (lane >> 4) * 8 + u * 2;
    wsu[t] = ((k < 40) ? 0x00003F80u : 0u) | ((k + 1 < 40) ? 0x3F800000u : 0u);
  } else if (t < OFF_STATS) {
    int r = t - OFF_MERGE; int j = r >> 6, d = r & 63;
    ws[t] = p.w_merge[d * 224 + j];
  } else if (t < OFF_COMB) {                // stats packed bf16 [383][32]
    int r = t - OFF_STATS;
    int j = r >> 5, pp = r & 31;
    wsu[t] = packrne(p.w_stats[(2 * pp) * 383 + j], p.w_stats[(2 * pp + 1) * 383 + j]);
  } else if (t < OFF_WO2) {                 // comb relayout [jq][n][c]
    int r = t - OFF_COMB;
    int jq = r >> 10, rem = r & 1023;
    int n = rem >> 2, c = rem & 3;
    ws[t] = p.w_comb[n * 224 + jq * 4 + c];
  } else {                                  // wout tables packed bf16
    int r = t - OFF_WO2; int a = r >> 9; int rr = r & 511;
    int e = rr >> 4, u = rr & 15;
    const float* src = a ? p.t2h_wout : p.h2t_wout;
    wsu[t] = packrne(src[(2 * u) * 32 + e], src[(2 * u + 1) * 32 + e]);
  }
}

#define FMA4(acc, a4, w0, w1, w2, w3)                                   \
  acc.x += a4.x * w0.x + a4.y * w1.x + a4.z * w2.x + a4.w * w3.x;       \
  acc.y += a4.x * w0.y + a4.y * w1.y + a4.z * w2.y + a4.w * w3.y;       \
  acc.z += a4.x * w0.z + a4.y * w1.z + a4.z * w2.z + a4.w * w3.z;       \
  acc.w += a4.x * w0.w + a4.y * w1.w + a4.z * w2.w + a4.w * w3.w;

#define MFMA16(acc, a, b) acc = __builtin_amdgcn_mfma_f32_16x16x32_bf16(a, b, acc, 0, 0, 0)

// A-frag: row=lane&15(+16rt), k=(lane>>4)*8+e; C/D: col=lane&15, row=(lane>>4)*4+reg.
// K-dim garbage excluded by construction: PV a1 + R4.5 B loads are guarded,
// Vfrag k>=40 zeroed. All other stale reads are M-confined (safe even if NaN).
__global__ __launch_bounds__(TPB, 4) void enc_row(P p) {
  const int row = blockIdx.x;
  const int tid = threadIdx.x;
  const int lane = tid & 63, wq = tid >> 6;
  const int lane15 = lane & 15, lg = lane >> 4;

  __shared__ unsigned smem_u[SMEM_BYTES / 4];
  char* smem = (char*)smem_u;
  unsigned short* sAu = (unsigned short*)(smem + SA_OFF);
  unsigned short* sZu = (unsigned short*)(smem + Z_OFF);
  float* s_bnk = (float*)(smem + BNK_OFF);
  float* s_ht  = (float*)(smem + SHT_OFF);
  float* s_om  = (float*)(smem + SOM_OFF);
  float* s_sm  = (float*)(smem + SSM_OFF);
  float* s_cb  = (float*)(smem + SCB_OFF);
  float* s_r12 = (float*)(smem + R12_OFF);
  int*   s_cnt = (int*)(smem + SCNT_OFF);

  const float* orow = p.obs + (size_t)row * 2988;
  const float* ws = p.ws;
  const unsigned* wsu = (const unsigned*)ws;

  // ---- S1: stage s_ht, hist planes; small set feats (2-way j-split); inits ----
  if (tid < 165) s_ht[tid] = orow[tid];
  if (tid < 256) {
    // feats: hand/table/cap0/cap1, d=q>>1, jh=q&1 (lane pairs combine via shfl)
    int feat = tid >> 6, q = tid & 63;
    int d = q >> 1, jh = q & 1;
    const int offs[4] = {0, 43, 83, 123};
    const int dsts[4] = {0, 32, 64, 96};
    int off = offs[feat];
    float a = 0.f;
    for (int j = jh * 20; j < jh * 20 + 20; ++j)
      a += orow[off + j] * p.ce[j * 32 + d];
    float other = __shfl_xor(a, 1, 64);
    if (jh == 0) s_sm[dsts[feat] + d] = a + other;
  } else if (tid < 272) {
    int d = tid - 256;
    float a = p.bch[d];
    for (int j = 0; j < 3; ++j) a += orow[40 + j] * p.wch[d * 3 + j];
    s_sm[192 + d] = fmaxf(a, 0.f);
  } else if (tid < 288) {
    int d = tid - 272;
    float a = p.bcc[d];
    for (int j = 0; j < 2; ++j) a += orow[163 + j] * p.wcc[d * 2 + j];
    s_sm[208 + d] = fmaxf(a, 0.f);
  } else if (tid < 352) {
    s_sm[128 + tid - 288] = 0.f;
  } else if (tid < 480) {
    s_om[tid - 352] = 0.f;
  } else if (tid == 480) {
    int c = 0; for (int i = 0; i < 40; ++i) c += (orow[i] > 0.5f);
    s_cnt[0] = c;
  } else if (tid == 481) {
    int c = 0; for (int i = 0; i < 40; ++i) c += (orow[43 + i] > 0.5f);
    s_cnt[1] = c;
  }
  if (tid < 64) s_cb[128 + tid] = p.b_stats[tid];
  else if (tid < 128) s_cb[tid - 64] = p.b_merge[tid - 64];
  else if (tid < 256) s_bnk[tid - 128] = 0.f;
  // hist -> bf16 hi/lo planes (rows 0..39, cols 61..63 zero)
  for (int m = tid; m < 2560; m += TPB) {
    int i = m >> 6, j = m & 63;
    float val = (j < 61) ? orow[165 + i * 61 + j] : 0.f;
    unsigned hb = __float_as_uint(val) & 0xFFFF0000u;
    *(unsigned short*)(smem + HISTH_OFF + i * 136 + j * 2) = (unsigned short)(hb >> 16);
    float rr = val - __uint_as_float(hb);
    *(unsigned short*)(smem + HISTL_OFF + i * 136 + j * 2) =
        (unsigned short)(__float_as_uint(rr) >> 16);
  }
  __syncthreads();
  #define OB(i) s_ht[i]

  // ---- R3: hseq MFMA (12 tasks) + card attn (320, global CV) + stats (192) ----
  for (int t = wq; t < 12; t += 8) {
    int rt = t % 3, nt = t / 3;
    int n = nt * 16 + lane15;
    int arow = rt * 16 + lane15;
    f32x4 acc;
    #pragma unroll
    for (int r = 0; r < 4; ++r) {
      int i = rt * 16 + lg * 4 + r;
      if (i < 40) {
        unsigned pb = wsu[OFF_POSB + i * 32 + (n >> 1)];
        acc[r] = (n & 1) ? bf_hi(pb) : bf_lo(pb);
      } else acc[r] = 0.f;
    }
    #pragma unroll
    for (int kt = 0; kt < 2; ++kt) {
      int kb = kt * 32 + lg * 8;
      bf16x8 aH = ld_b64x2(smem + HISTH_OFF + arow * 136 + kb * 2);
      bf16x8 aL = ld_b64x2(smem + HISTL_OFF + arow * 136 + kb * 2);
      bf16x8 bH = *(const bf16x8*)(wsu + OFF_FRHP + kt * 1024 + nt * 256 + lane * 4);
      bf16x8 bL = *(const bf16x8*)(wsu + OFF_FRHP + 2048 + kt * 1024 + nt * 256 + lane * 4);
      MFMA16(acc, aH, bH); MFMA16(acc, aH, bL); MFMA16(acc, aL, bH);
    }
    #pragma unroll
    for (int r = 0; r < 4; ++r) {
      int i = rt * 16 + lg * 4 + r;
      if (i < 40) {
        sAu[i * 64 + n] = bf16rne(acc[r]);
        unsigned hb = __float_as_uint(acc[r]) & 0xFFFF0000u;
        *(unsigned short*)(smem + DH_OFF + i * 144 + n * 2) = (unsigned short)(hb >> 16);
        float rr = acc[r] - __uint_as_float(hb);
        *(unsigned short*)(smem + DL_OFF + i * 144 + n * 2) =
            (unsigned short)(__float_as_uint(rr) >> 16);
      }
    }
  }
  if (tid < 320) {
    // card attn: s = qm*km*G[i][j] + qm*u[i] + km*v[j] + c (tables pre-scaled)
    int a = tid / 160, r = tid - a * 160;
    int h = r / 40, i = r - h * 40;
    int qoff = a ? 43 : 0, koff = a ? 0 : 43;
    float qm = OB(qoff + i);
    const unsigned* Gp = wsu + OFF_G + ((a * 4 + h) * 40 + i) * 20;
    const float* vp = ws + OFF_V + (a * 4 + h) * 40;
    const float* Cv = ws + OFF_CV + a * 1280;   // global (L2-resident)
    const float* bin = a ? p.t2h_bin : p.h2t_bin;
    float base = ws[OFF_CTB + a * 4 + h] + qm * ws[OFF_U + (a * 4 + h) * 40 + i];
    const int e0 = h * 8;
    float den = 0.f;
    float o0 = 0.f, o1 = 0.f, o2 = 0.f, o3 = 0.f;
    float o4 = 0.f, o5 = 0.f, o6 = 0.f, o7 = 0.f;
    for (int j = 0; j < 40; ++j) {
      float km = OB(koff + j);
      if (km > 0.5f) {
        unsigned g2 = Gp[j >> 1];
        float gj = (j & 1) ? bf_hi(g2) : bf_lo(g2);
        float s = fmaf(km, fmaf(qm, gj, vp[j]), base);
        float pj = __expf(s);
        den += pj;
        float pk = pj * km;
        float4 v0 = *(const float4*)(Cv + j * 32 + e0);
        float4 v1 = *(const float4*)(Cv + j * 32 + e0 + 4);
        o0 += pk * v0.x; o1 += pk * v0.y; o2 += pk * v0.z; o3 += pk * v0.w;
        o4 += pk * v1.x; o5 += pk * v1.y; o6 += pk * v1.z; o7 += pk * v1.w;
      }
    }
    if (qm > 0.5f) {
      float inv = 1.f / den;
      float4 bv0 = *(const float4*)(bin + 64 + e0);
      float4 bv1 = *(const float4*)(bin + 64 + e0 + 4);
      float* om = s_om + (i & 1) * 64 + a * 32 + e0;  // even/odd-i banks
      atomicAdd(&om[0], o0 * inv + bv0.x);
      atomicAdd(&om[1], o1 * inv + bv0.y);
      atomicAdd(&om[2], o2 * inv + bv0.z);
      atomicAdd(&om[3], o3 * inv + bv0.w);
      atomicAdd(&om[4], o4 * inv + bv1.x);
      atomicAdd(&om[5], o5 * inv + bv1.y);
      atomicAdd(&om[6], o6 * inv + bv1.z);
      atomicAdd(&om[7], o7 * inv + bv1.w);
    }
  } else {
    // stats 12-way j-split, packed bf16 weights, 2 accumulation banks
    int r = tid - 320;
    int c = r >> 4, d0 = (r & 15) << 2;
    int j0 = c << 5, j1 = (c == 11) ? 383 : j0 + 32;
    const float* st = orow + 2605;
    const unsigned* wt = wsu + OFF_STATS + (d0 >> 1);
    float x0 = 0.f, x1 = 0.f, x2 = 0.f, x3 = 0.f;
    for (int j = j0; j < j1; ++j) {
      float a0 = st[j];
      unsigned u0 = wt[j * 32], u1 = wt[j * 32 + 1];
      x0 += a0 * bf_lo(u0); x1 += a0 * bf_hi(u0);
      x2 += a0 * bf_lo(u1); x3 += a0 * bf_hi(u1);
    }
    float* bank = (c & 1) ? s_bnk : (s_cb + 128);
    atomicAdd(&bank[d0 + 0], x0);
    atomicAdd(&bank[d0 + 1], x1);
    atomicAdd(&bank[d0 + 2], x2);
    atomicAdd(&bank[d0 + 3], x3);
  }
  __syncthreads();

  // ---- R4: MFMA QKV; Q->QPL, K->KF, V->Vfrag bf16 (+k>=40 zeros);
  //      attn-mean (tid 448..479, 2-way e-split) ----
  for (int t = wq; t < 36; t += 8) {
    int rt = t % 3, nt = t / 3;            // nt 0..11 (Q 0..3, K 4..7, V 8..11)
    int n = nt * 16 + lane15;
    int arow = rt * 16 + lane15;
    float bia = p.enc_bin[n];
    f32x4 acc = {bia, bia, bia, bia};
    #pragma unroll
    for (int kt = 0; kt < 2; ++kt) {
      int kb = kt * 32 + lg * 8;
      bf16x8 aH = *(const bf16x8*)(smem + DH_OFF + arow * 144 + kb * 2);
      bf16x8 aL = *(const bf16x8*)(smem + DL_OFF + arow * 144 + kb * 2);
      bf16x8 bH = *(const bf16x8*)(wsu + OFF_FRAG + FR_QKV + kt * 3072 + nt * 256 + lane * 4);
      bf16x8 bL = *(const bf16x8*)(wsu + OFF_FRAG + FR_QKV + 6144 + kt * 3072 + nt * 256 + lane * 4);
      MFMA16(acc, aH, bH); MFMA16(acc, aH, bL); MFMA16(acc, aL, bH);
    }
    if (nt < 4) {            // Q hi plane [h=nt][i<40][e]
      #pragma unroll
      for (int r = 0; r < 4; ++r) {
        int i = rt * 16 + lg * 4 + r;
        if (i < 40)
          *(unsigned short*)(smem + QPL_OFF + ((nt * 40 + i) * 16 + lane15) * 2) =
              bf16rne(acc[r]);
      }
    } else if (nt < 8) {     // K -> B-frag [h][jt][lane'][us]
      int h = nt - 4, e = lane15;
      int lp = (e >> 3) << 4, us = e & 7;
      #pragma unroll
      for (int r = 0; r < 4; ++r) {
        int j = rt * 16 + lg * 4 + r;
        if (j < 40) {
          int lanep = lp + (j & 15);
          *(unsigned short*)(smem + KF_OFF +
              (((h * 3 + (j >> 4)) * 32 + lanep) * 8 + us) * 2) = bf16rne(acc[r]);
        }
      }
    } else {                 // V -> B-frag bf16 [h][kt][lane'][us] (rows j)
      int h = nt - 8, e = lane15;
      #pragma unroll
      for (int r = 0; r < 4; ++r) {
        int j = rt * 16 + lg * 4 + r;
        if (j < 40) {
          int kt = j >> 5, k_ = j & 31;
          int lanep = ((k_ >> 3) << 4) | e;
          *(unsigned short*)(smem + VF_OFF +
              (((h * 2 + kt) * 64 + lanep) * 8 + (k_ & 7)) * 2) = bf16rne(acc[r]);
        }
      }
    }
  }
  // Vfrag kt=1 lanes 16..63 (k 40..63) zeros: 768 u32
  for (int m = tid; m < 768; m += TPB) {
    int h = m / 192, rem = m - h * 192;
    ((unsigned*)(smem + VF_OFF))[(h * 2 + 1) * 256 + 64 + rem] = 0u;
  }
  if (tid >= 448 && tid < 480) {  // attn-mean feats (2-way e-split, atomicAdd)
    int r = tid - 448;
    int a = r >> 4, q = r & 15;
    int d0 = (q >> 1) << 2, eh = q & 1;
    int ch = s_cnt[0], ct = s_cnt[1];
    if (ch > 0 && ct > 0) {
      float ic = 1.f / (float)(a ? ct : ch);
      const unsigned* wt = wsu + OFF_WO2 + a * 512 + (d0 >> 1);
      float4 v = make_float4(0.f, 0.f, 0.f, 0.f);
      if (eh == 0) v = *(const float4*)((a ? p.t2h_bout : p.h2t_bout) + d0);
      for (int e = eh * 16; e < eh * 16 + 16; ++e) {
        float oe = (s_om[a * 32 + e] + s_om[64 + a * 32 + e]) * ic;
        unsigned w01 = wt[e * 16], w23 = wt[e * 16 + 1];
        v.x += oe * bf_lo(w01); v.y += oe * bf_hi(w01);
        v.z += oe * bf_lo(w23); v.w += oe * bf_hi(w23);
      }
      atomicAdd(&s_sm[128 + a * 32 + d0 + 0], v.x);
      atomicAdd(&s_sm[128 + a * 32 + d0 + 1], v.y);
      atomicAdd(&s_sm[128 + a * 32 + d0 + 2], v.z);
      atomicAdd(&s_sm[128 + a * 32 + d0 + 3], v.w);
    }
  }
  __syncthreads();

  // ---- R4.5: S = QK^T via MFMA (B k>=16 guarded to zero); P = bf16(exp(s/4)) ----
  for (int t = wq; t < 36; t += 8) {
    int h = t / 9, rr = t % 9;
    int rt = rr / 3, nt = rr % 3;
    int arow = rt * 16 + lane15;
    f32x4 acc = {0.f, 0.f, 0.f, 0.f};
    bf16x8 aH = *(const bf16x8*)(smem + QPL_OFF + ((h * 40 + arow) * 16 + (lg & 1) * 8) * 2);
    bf16x8 bH = {0, 0, 0, 0, 0, 0, 0, 0};     // k 16..31 zero
    if (lane < 32)
      bH = *(const bf16x8*)(smem + KF_OFF + (((h * 3 + nt) * 32 + lane) * 8) * 2);
    MFMA16(acc, aH, bH);
    int j = nt * 16 + lane15;
    if (j < 40) {
      #pragma unroll
      for (int r = 0; r < 4; ++r) {
        int i = rt * 16 + lg * 4 + r;
        if (i < 40)
          *(unsigned short*)(smem + P_OFF + h * 3200 + i * 80 + j * 2) =
              bf16rne(__expf(acc[r] * 0.25f));
      }
    }
  }
  __syncthreads();

  // ---- R5: PV via MFMA (den via ones-frag) -> OH; merge matvec (256..383) ----
  {
    bf16x8 ones0 = *(const bf16x8*)(wsu + OFF_ONES + lane * 4);
    bf16x8 ones1 = *(const bf16x8*)(wsu + OFF_ONES + 256 + lane * 4);
    for (int t = wq; t < 12; t += 8) {
      int h = t / 3, rt = t % 3;
      int arow = rt * 16 + lane15;
      const char* pb = smem + P_OFF + h * 3200 + arow * 80;
      bf16x8 a0 = *(const bf16x8*)(pb + lg * 16);      // k 0..31: in-row
      bf16x8 a1 = {0, 0, 0, 0, 0, 0, 0, 0};           // k 40..63 slots = 0
      if (lg == 0) a1 = *(const bf16x8*)(pb + 64);    // k 32..39: in-row only
      bf16x8 v0 = *(const bf16x8*)(smem + VF_OFF + ((h * 2 + 0) * 64 + lane) * 16);
      bf16x8 v1 = *(const bf16x8*)(smem + VF_OFF + ((h * 2 + 1) * 64 + lane) * 16);
      f32x4 accV = {0.f, 0.f, 0.f, 0.f}, accD = {0.f, 0.f, 0.f, 0.f};
      MFMA16(accV, a0, v0); MFMA16(accV, a1, v1);
      MFMA16(accD, a0, ones0); MFMA16(accD, a1, ones1);
      #pragma unroll
      for (int r = 0; r < 4; ++r) {
        int i = rt * 16 + lg * 4 + r;
        if (i < 40) {
          float o = accV[r] / accD[r];
          *(unsigned short*)(smem + OH_OFF + (i * 72 + h * 16 + lane15) * 2) =
              bf16rne(o);
        }
      }
    }
  }
  if (tid >= 256 && tid < 384) {   // set_merge matvec, 8-way j-split, 2 banks
    int r = tid - 256;
    int d0 = (r & 15) << 2, jc = r >> 4;
    const float* wt = ws + OFF_MERGE + d0;
    float4 acc = make_float4(0.f, 0.f, 0.f, 0.f);
    int j0 = jc * 28;
    for (int j = j0; j < j0 + 28; j += 4) {
      float4 a4 = *(const float4*)(s_sm + j);
      float4 w0 = *(const float4*)(wt + j * 64);
      float4 w1 = *(const float4*)(wt + (j + 1) * 64);
      float4 w2 = *(const float4*)(wt + (j + 2) * 64);
      float4 w3 = *(const float4*)(wt + (j + 3) * 64);
      FMA4(acc, a4, w0, w1, w2, w3);
    }
    float* bank = (jc & 1) ? (s_bnk + 64) : s_cb;
    atomicAdd(&bank[d0 + 0], acc.x);
    atomicAdd(&bank[d0 + 1], acc.y);
    atomicAdd(&bank[d0 + 2], acc.z);
    atomicAdd(&bank[d0 + 3], acc.w);
  }
  __syncthreads();

  // ---- R6: MFMA out-proj (OH) + residual(sA bf16) -> preLN1 bf16 at Z ----
  for (int t = wq; t < 12; t += 8) {
    int rt = t % 3, nt = t / 3;
    int n = nt * 16 + lane15;
    int arow = rt * 16 + lane15;
    f32x4 acc;
    #pragma unroll
    for (int r = 0; r < 4; ++r) {
      int i = rt * 16 + lg * 4 + r;
      acc[r] = p.enc_bout[n] + ((i < 40) ? bfus(sAu[i * 64 + n]) : 0.f);
    }
    #pragma unroll
    for (int kt = 0; kt < 2; ++kt) {
      int kb = kt * 32 + lg * 8;
      bf16x8 aH = *(const bf16x8*)(smem + OH_OFF + arow * 144 + kb * 2);
      bf16x8 bH = *(const bf16x8*)(wsu + OFF_FRAG + FR_OUT + kt * 1024 + nt * 256 + lane * 4);
      bf16x8 bL = *(const bf16x8*)(wsu + OFF_FRAG + FR_OUT + 2048 + kt * 1024 + nt * 256 + lane * 4);
      MFMA16(acc, aH, bH); MFMA16(acc, aH, bL);
    }
    #pragma unroll
    for (int r = 0; r < 4; ++r) {
      int i = rt * 16 + lg * 4 + r;
      if (i < 40) sZu[i * 64 + n] = bf16rne(acc[r]);
    }
  }
  __syncthreads();

  // ---- R7: LN1 -> sA bf16 + hi/lo planes at DH/DL ----
  {
    float g = p.ln1_g[lane], b = p.ln1_b[lane];
    for (int i = wq; i < 40; i += 8) {
      float x = bfus(sZu[(i << 6) + lane]);
      float s = x;
      #pragma unroll
      for (int off = 32; off; off >>= 1) s += __shfl_xor(s, off, 64);
      float m = s * 0.015625f;
      float xm = x - m;
      float v = xm * xm;
      #pragma unroll
      for (int off = 32; off; off >>= 1) v += __shfl_xor(v, off, 64);
      float rs = rsqrtf(v * 0.015625f + 1e-5f);
      float val = xm * rs * g + b;
      sAu[(i << 6) + lane] = bf16rne(val);
      unsigned hb = __float_as_uint(val) & 0xFFFF0000u;
      *(unsigned short*)(smem + DH_OFF + i * 144 + lane * 2) = (unsigned short)(hb >> 16);
      float rr = val - __uint_as_float(hb);
      *(unsigned short*)(smem + DL_OFF + i * 144 + lane * 2) =
          (unsigned short)(__float_as_uint(rr) >> 16);
    }
  }
  __syncthreads();

  // ---- R8: MFMA FF1 + relu -> hi-only bf16 [40][136]us at X (i<40 guard) ----
  for (int t = wq; t < 24; t += 8) {
    int rt = t % 3, nt = t / 3;            // nt 0..7
    int n = nt * 16 + lane15;
    int arow = rt * 16 + lane15;
    float bia = p.b_ff1[n];
    f32x4 acc = {bia, bia, bia, bia};
    #pragma unroll
    for (int kt = 0; kt < 2; ++kt) {
      int kb = kt * 32 + lg * 8;
      bf16x8 aH = *(const bf16x8*)(smem + DH_OFF + arow * 144 + kb * 2);
      bf16x8 aL = *(const bf16x8*)(smem + DL_OFF + arow * 144 + kb * 2);
      bf16x8 bH = *(const bf16x8*)(wsu + OFF_FRAG + FR_FF1 + kt * 2048 + nt * 256 + lane * 4);
      bf16x8 bL = *(const bf16x8*)(wsu + OFF_FRAG + FR_FF1 + 4096 + kt * 2048 + nt * 256 + lane * 4);
      MFMA16(acc, aH, bH); MFMA16(acc, aH, bL); MFMA16(acc, aL, bH);
    }
    #pragma unroll
    for (int r = 0; r < 4; ++r) {
      int i = rt * 16 + lg * 4 + r;
      if (i < 40) {   // guard: rows 40-47 would stomp live DH/DL
        float v = fmaxf(acc[r], 0.f);
        *(unsigned short*)(smem + FF1P_OFF + i * 272 + n * 2) = bf16rne(v);
      }
    }
  }
  __syncthreads();

  // ---- R9: MFMA FF2 + residual(sA bf16) -> preLN2 bf16 at Z ----
  for (int t = wq; t < 12; t += 8) {
    int rt = t % 3, nt = t / 3;
    int n = nt * 16 + lane15;
    int arow = rt * 16 + lane15;
    f32x4 acc;
    #pragma unroll
    for (int r = 0; r < 4; ++r) {
      int i = rt * 16 + lg * 4 + r;
      acc[r] = p.b_ff2[n] + ((i < 40) ? bfus(sAu[i * 64 + n]) : 0.f);
    }
    #pragma unroll
    for (int kt = 0; kt < 4; ++kt) {
      int kb = kt * 32 + lg * 8;
      bf16x8 aH = *(const bf16x8*)(smem + FF1P_OFF + arow * 272 + kb * 2);
      bf16x8 bH = *(const bf16x8*)(wsu + OFF_FRAG + FR_FF2 + kt * 1024 + nt * 256 + lane * 4);
      bf16x8 bL = *(const bf16x8*)(wsu + OFF_FRAG + FR_FF2 + 4096 + kt * 1024 + nt * 256 + lane * 4);
      MFMA16(acc, aH, bH); MFMA16(acc, aH, bL);
    }
    #pragma unroll
    for (int r = 0; r < 4; ++r) {
      int i = rt * 16 + lg * 4 + r;
      if (i < 40) sZu[i * 64 + n] = bf16rne(acc[r]);
    }
  }
  __syncthreads();

  // ---- R10: LN2 -> sA bf16 ----
  {
    float g = p.ln2_g[lane], b = p.ln2_b[lane];
    for (int i = wq; i < 40; i += 8) {
      float x = bfus(sZu[(i << 6) + lane]);
      float s = x;
      #pragma unroll
      for (int off = 32; off; off >>= 1) s += __shfl_xor(s, off, 64);
      float m = s * 0.015625f;
      float xm = x - m;
      float v = xm * xm;
      #pragma unroll
      for (int off = 32; off; off >>= 1) v += __shfl_xor(v, off, 64);
      float rs = rsqrtf(v * 0.015625f + 1e-5f);
      sAu[(i << 6) + lane] = bf16rne(xm * rs * g + b);
    }
  }
  __syncthreads();

  // ---- R11: hist mean + stats/merge bank-combine + relu + seat_feat ----
  if (tid < 64) {
    float a = 0.f;
    for (int i = 0; i < 40; ++i) a += bfus(sAu[(i << 6) + tid]);
    s_cb[64 + tid] = a * 0.025f;
    s_cb[128 + tid] = fmaxf(s_cb[128 + tid] + s_bnk[tid], 0.f);
    s_cb[tid] = fmaxf(s_cb[tid] + s_bnk[64 + tid], 0.f);
  } else if (tid < 96) {
    int d = tid - 64;
    const float* sv = p.seat + (size_t)row * 6;
    float acc = p.b_seat[d];
    for (int j = 0; j < 6; ++j) acc += sv[j] * p.w_seat[d * 6 + j];
    s_cb[192 + d] = fmaxf(acc, 0.f);
  }
  __syncthreads();

  // ---- R12: final 224 -> 256 matvec (vectorized comb layout), 2-way j-split.
  //      Partials overlay dead s_ht/s_om/s_sm. ----
  {
    int n = tid & 255, half = tid >> 8;
    const float* wt = ws + OFF_COMB + n * 4;
    float acc = half ? 0.f : p.b_comb[n];
    int jq0 = half * 28;
    for (int jq = jq0; jq < jq0 + 28; ++jq) {
      float4 a4 = *(const float4*)(s_cb + jq * 4);
      float4 w = *(const float4*)(wt + jq * 1024);
      acc += a4.x * w.x + a4.y * w.y + a4.z * w.z + a4.w * w.w;
    }
    s_r12[half * 256 + n] = acc;
  }
  __syncthreads();
  if (tid < 256)
    p.out[(size_t)row * 256 + tid] = fmaxf(s_r12[tid] + s_r12[256 + tid], 0.f);
  #undef OB
}

extern "C" void kernel_launch(void* const* d_in, const int* in_sizes, int n_in,
                              void* d_out, int out_size, void* d_ws, size_t ws_size,
                              hipStream_t stream) {
  typedef const float* F;
  P p;
  p.obs      = (F)d_in[0];
  p.seat     = (F)d_in[1];
  p.ce       = (F)d_in[2];
  p.wch      = (F)d_in[3];
  p.bch      = (F)d_in[4];
  p.wcc      = (F)d_in[5];
  p.bcc      = (F)d_in[6];
  p.h2t_win  = (F)d_in[7];
  p.h2t_bin  = (F)d_in[8];
  p.h2t_wout = (F)d_in[9];
  p.h2t_bout = (F)d_in[10];
  p.t2h_win  = (F)d_in[11];
  p.t2h_bin  = (F)d_in[12];
  p.t2h_wout = (F)d_in[13];
  p.t2h_bout = (F)d_in[14];
  p.w_merge  = (F)d_in[15];
  p.b_merge  = (F)d_in[16];
  p.w_hproj  = (F)d_in[17];
  p.b_hproj  = (F)d_in[18];
  p.pos      = (F)d_in[19];
  p.enc_win  = (F)d_in[20];
  p.enc_bin  = (F)d_in[21];
  p.enc_wout = (F)d_in[22];
  p.enc_bout = (F)d_in[23];
  p.ln1_g    = (F)d_in[24];
  p.ln1_b    = (F)d_in[25];
  p.w_ff1    = (F)d_in[26];
  p.b_ff1    = (F)d_in[27];
  p.w_ff2    = (F)d_in[28];
  p.b_ff2    = (F)d_in[29];
  p.ln2_g    = (F)d_in[30];
  p.ln2_b    = (F)d_in[31];
  p.w_stats  = (F)d_in[32];
  p.b_stats  = (F)d_in[33];
  p.w_seat   = (F)d_in[34];
  p.b_seat   = (F)d_in[35];
  p.w_comb   = (F)d_in[36];
  p.b_comb   = (F)d_in[37];
  p.ws  = (const float*)d_ws;
  p.out = (float*)d_out;

  const int Bn = in_sizes[0] / 2988;
  hipLaunchKernelGGL(prep_kernel, dim3((WS_TOTAL + 255) / 256), dim3(256), 0, stream,
                     p, (float*)d_ws);
  hipLaunchKernelGGL(enc_row, dim3(Bn), dim3(TPB), 0, stream, p);
}